// Round 4
// baseline (779.490 us; speedup 1.0000x reference)
//
#include <hip/hip_runtime.h>
#include <hip/hip_bf16.h>
#include <math.h>

// Problem constants (H=1024, E=8, I=4096, T=B*S=4096)
#define H_DIM 1024
#define E_NUM 8
#define I_DIM 4096
#define T_NUM 4096
#define CAP   8192   // 2*T worst-case pairs per expert

typedef __attribute__((ext_vector_type(8))) short bf16x8;
typedef __attribute__((ext_vector_type(4))) float f32x4;

typedef const __attribute__((address_space(1))) void* gptr_t;
typedef __attribute__((address_space(3))) void* lptr_t;

__device__ inline unsigned short f2bf(float f) {
  union { __hip_bfloat16 h; unsigned short u; } cv;
  cv.h = __float2bfloat16(f);   // RNE
  return cv.u;
}

// ---------------- Router: 1 wave per token (also emits xb = bf16(x)) ----------------
__global__ void router_kernel(const float* __restrict__ x,
                              const float* __restrict__ gw,
                              const float* __restrict__ gb,
                              int* __restrict__ cnt,
                              int* __restrict__ list,
                              float* __restrict__ tokw,
                              unsigned short* __restrict__ xb) {
  const int t = blockIdx.x;
  const int l = threadIdx.x;
  const float* xr = x + (size_t)t * H_DIM;
  float acc[E_NUM];
#pragma unroll
  for (int e = 0; e < E_NUM; ++e) acc[e] = 0.f;
#pragma unroll
  for (int j = 0; j < H_DIM / 64; ++j) {
    const int h = l + j * 64;
    const float xv = xr[h];
    if (xb) xb[(size_t)t * H_DIM + h] = f2bf(xv);
    const float4* g = (const float4*)(gw + (size_t)h * E_NUM);
    const float4 g0 = g[0], g1 = g[1];
    acc[0] += xv * g0.x; acc[1] += xv * g0.y; acc[2] += xv * g0.z; acc[3] += xv * g0.w;
    acc[4] += xv * g1.x; acc[5] += xv * g1.y; acc[6] += xv * g1.z; acc[7] += xv * g1.w;
  }
#pragma unroll
  for (int off = 32; off > 0; off >>= 1) {
#pragma unroll
    for (int e = 0; e < E_NUM; ++e) acc[e] += __shfl_down(acc[e], off, 64);
  }
  if (l == 0) {
    float lg[E_NUM], mx = -1e30f;
#pragma unroll
    for (int e = 0; e < E_NUM; ++e) { lg[e] = acc[e] + gb[e]; mx = fmaxf(mx, lg[e]); }
    float p[E_NUM], s = 0.f;
#pragma unroll
    for (int e = 0; e < E_NUM; ++e) { p[e] = expf(lg[e] - mx); s += p[e]; }
    const float inv = 1.f / s;
#pragma unroll
    for (int e = 0; e < E_NUM; ++e) p[e] *= inv;
    int i0 = 0;
#pragma unroll
    for (int e = 1; e < E_NUM; ++e) if (p[e] > p[i0]) i0 = e;
    int i1 = (i0 == 0) ? 1 : 0;
#pragma unroll
    for (int e = 0; e < E_NUM; ++e) if (e != i0 && p[e] > p[i1]) i1 = e;
    const float denom = p[i0] + p[i1] + 1e-6f;
    const float w0 = p[i0] / denom, w1 = p[i1] / denom;
    int pos = atomicAdd(&cnt[i0], 1);
    list[i0 * CAP + pos] = t * 2;
    tokw[t * 2] = w0;
    pos = atomicAdd(&cnt[i1], 1);
    list[i1 * CAP + pos] = t * 2 + 1;
    tokw[t * 2 + 1] = w1;
  }
}

// ---------------- Scan ----------------
__global__ void scan_kernel(const int* __restrict__ cnt, int* __restrict__ base) {
  if (threadIdx.x == 0 && blockIdx.x == 0) {
    int b = 0;
    for (int e = 0; e < E_NUM; ++e) { base[e] = b; b += cnt[e]; }
  }
}

// ---------------- per-expert fp32 [R][C] -> bf16 [C][R] (k-contiguous) ----------------
__launch_bounds__(256)
__global__ void transpose_cvt_kernel(const float* __restrict__ src,
                                     unsigned short* __restrict__ dst,
                                     int R, int C) {
  const int e = blockIdx.z;
  const int r0 = blockIdx.y * 32;
  const int c0 = blockIdx.x * 128;
  const float* s = src + (size_t)e * R * C;
  unsigned short* d = dst + (size_t)e * R * C;
  __shared__ unsigned short Lt[32 * 130];
  const int tid = threadIdx.x;
#pragma unroll
  for (int m = 0; m < 4; ++m) {
    const int li = tid + m * 256;
    const int r = li >> 5;
    const int cg = (li & 31) * 4;
    const float4 v = *(const float4*)(s + (size_t)(r0 + r) * C + c0 + cg);
    Lt[r * 130 + cg + 0] = f2bf(v.x);
    Lt[r * 130 + cg + 1] = f2bf(v.y);
    Lt[r * 130 + cg + 2] = f2bf(v.z);
    Lt[r * 130 + cg + 3] = f2bf(v.w);
  }
  __syncthreads();
#pragma unroll
  for (int m = 0; m < 2; ++m) {
    const int li = tid + m * 256;
    const int col = li >> 2;
    const int rg = (li & 3) * 8;
    unsigned short tmp[8];
#pragma unroll
    for (int j = 0; j < 8; ++j) tmp[j] = Lt[(rg + j) * 130 + col];
    *(f32x4*)(d + (size_t)(c0 + col) * R + r0 + rg) = *(const f32x4*)tmp;
  }
}

// ---------------- Stage 1: hmid = gelu(xb @ W1t^T + b1), BK=64, swizzled LDS ----------------
__launch_bounds__(256)
__global__ void gemm1_pre_kernel(const unsigned short* __restrict__ xb,
                                 const unsigned short* __restrict__ W1t,
                                 const float* __restrict__ b1,
                                 const int* __restrict__ cnt,
                                 const int* __restrict__ base,
                                 const int* __restrict__ list,
                                 unsigned short* __restrict__ hmid) {
  const int e = blockIdx.z;
  const int c = cnt[e];
  const int m0 = blockIdx.y * 128;
  if (m0 >= c) return;
  const int n0 = blockIdx.x * 128;

  __shared__ int toks[128];
  __shared__ __align__(16) unsigned short As[128 * 64];
  __shared__ __align__(16) unsigned short Bs[128 * 64];

  const int tid = threadIdx.x;
  if (tid < 128) {
    int idx = m0 + tid; if (idx >= c) idx = c - 1;
    toks[tid] = list[e * CAP + idx] >> 1;
  }
  __syncthreads();

  const int lane = tid & 63;
  const int wave = tid >> 6;
  const int wm = (wave >> 1) * 64;
  const int wn = (wave & 1) * 64;
  const int l16 = lane & 15;
  const int quad = lane >> 4;
  const int sw = (quad ^ (l16 & 7)) * 8;  // swizzled k-elem offset (kh=0)

  const unsigned short* W1e = W1t + (size_t)e * H_DIM * I_DIM;  // [I][H]

  // Staging: chunk cch = r*256+tid, row=cch>>3, slot j=cch&7 holds global chunk j^(row&7)
  const unsigned short* aSrc[4];
  unsigned boff[4];
#pragma unroll
  for (int r = 0; r < 4; ++r) {
    const int cch = r * 256 + tid;
    const int row = cch >> 3;
    const int g = (cch & 7) ^ (row & 7);
    aSrc[r] = xb + (size_t)toks[row] * H_DIM + g * 8;
    boff[r] = (unsigned)(n0 + row) * H_DIM + g * 8;
  }
  char* aDstB = (char*)As + wave * 1024;
  char* bDstB = (char*)Bs + wave * 1024;

  f32x4 acc[16];
#pragma unroll
  for (int i = 0; i < 16; ++i) acc[i] = (f32x4){0.f, 0.f, 0.f, 0.f};

  for (int k0 = 0; k0 < H_DIM; k0 += 64) {
#pragma unroll
    for (int r = 0; r < 4; ++r)
      __builtin_amdgcn_global_load_lds((gptr_t)(aSrc[r] + k0), (lptr_t)(aDstB + r * 4096), 16, 0, 0);
#pragma unroll
    for (int r = 0; r < 4; ++r)
      __builtin_amdgcn_global_load_lds((gptr_t)(W1e + boff[r] + k0), (lptr_t)(bDstB + r * 4096), 16, 0, 0);
    __syncthreads();
#pragma unroll
    for (int kh = 0; kh < 2; ++kh) {
      const int ko = sw ^ (kh * 32);
      bf16x8 a[4], b[4];
#pragma unroll
      for (int mf = 0; mf < 4; ++mf)
        a[mf] = *(const bf16x8*)&As[(wm + mf * 16 + l16) * 64 + ko];
#pragma unroll
      for (int nf = 0; nf < 4; ++nf)
        b[nf] = *(const bf16x8*)&Bs[(wn + nf * 16 + l16) * 64 + ko];
#pragma unroll
      for (int mf = 0; mf < 4; ++mf)
#pragma unroll
        for (int nf = 0; nf < 4; ++nf)
          acc[mf * 4 + nf] = __builtin_amdgcn_mfma_f32_16x16x32_bf16(
              a[mf], b[nf], acc[mf * 4 + nf], 0, 0, 0);
    }
    __syncthreads();
  }

  const int hb = base[e];
#pragma unroll
  for (int mf = 0; mf < 4; ++mf) {
#pragma unroll
    for (int reg = 0; reg < 4; ++reg) {
      const int row = wm + mf * 16 + quad * 4 + reg;
      const int gr = m0 + row;
      if (gr < c) {
#pragma unroll
        for (int nf = 0; nf < 4; ++nf) {
          const int col = n0 + wn + nf * 16 + l16;
          const float v = acc[mf * 4 + nf][reg] + b1[e * I_DIM + col];
          const float u = v + 0.044715f * v * v * v;
          const float g = v / (1.f + __expf(-1.5957691216057308f * u));
          hmid[(size_t)(hb + gr) * I_DIM + col] = f2bf(g);
        }
      }
    }
  }
}

// ---------------- Stage 2: out += w*(hmid @ W2t^T + b2), BK=64, split-K=2 ----------------
__launch_bounds__(256)
__global__ void gemm2_pre_kernel(const unsigned short* __restrict__ hmid,
                                 const unsigned short* __restrict__ W2t,
                                 const float* __restrict__ b2,
                                 const int* __restrict__ cnt,
                                 const int* __restrict__ base,
                                 const int* __restrict__ list,
                                 const float* __restrict__ tokw,
                                 float* __restrict__ out) {
  const int e = blockIdx.z;
  const int c = cnt[e];
  const int m0 = blockIdx.y * 128;
  if (m0 >= c) return;
  const int n0 = (blockIdx.x & 7) * 128;
  const int split = blockIdx.x >> 3;            // 0..1
  const int kbeg = split * (I_DIM / 2);
  const int kend = kbeg + I_DIM / 2;

  __shared__ int ents[128];
  __shared__ int arow[128];
  __shared__ __align__(16) unsigned short As[128 * 64];
  __shared__ __align__(16) unsigned short Bs[128 * 64];

  const int tid = threadIdx.x;
  const int hb = base[e];
  if (tid < 128) {
    int idx = m0 + tid; if (idx >= c) idx = c - 1;
    ents[tid] = list[e * CAP + idx];
    arow[tid] = hb + idx;
  }
  __syncthreads();

  const int lane = tid & 63;
  const int wave = tid >> 6;
  const int wm = (wave >> 1) * 64;
  const int wn = (wave & 1) * 64;
  const int l16 = lane & 15;
  const int quad = lane >> 4;
  const int sw = (quad ^ (l16 & 7)) * 8;

  const unsigned short* W2e = W2t + (size_t)e * I_DIM * H_DIM;  // [H][I]

  const unsigned short* aSrc[4];
  unsigned boff[4];
#pragma unroll
  for (int r = 0; r < 4; ++r) {
    const int cch = r * 256 + tid;
    const int row = cch >> 3;
    const int g = (cch & 7) ^ (row & 7);
    aSrc[r] = hmid + (size_t)arow[row] * I_DIM + g * 8;
    boff[r] = (unsigned)(n0 + row) * I_DIM + g * 8;
  }
  char* aDstB = (char*)As + wave * 1024;
  char* bDstB = (char*)Bs + wave * 1024;

  f32x4 acc[16];
#pragma unroll
  for (int i = 0; i < 16; ++i) acc[i] = (f32x4){0.f, 0.f, 0.f, 0.f};

  for (int k0 = kbeg; k0 < kend; k0 += 64) {
#pragma unroll
    for (int r = 0; r < 4; ++r)
      __builtin_amdgcn_global_load_lds((gptr_t)(aSrc[r] + k0), (lptr_t)(aDstB + r * 4096), 16, 0, 0);
#pragma unroll
    for (int r = 0; r < 4; ++r)
      __builtin_amdgcn_global_load_lds((gptr_t)(W2e + boff[r] + k0), (lptr_t)(bDstB + r * 4096), 16, 0, 0);
    __syncthreads();
#pragma unroll
    for (int kh = 0; kh < 2; ++kh) {
      const int ko = sw ^ (kh * 32);
      bf16x8 a[4], b[4];
#pragma unroll
      for (int mf = 0; mf < 4; ++mf)
        a[mf] = *(const bf16x8*)&As[(wm + mf * 16 + l16) * 64 + ko];
#pragma unroll
      for (int nf = 0; nf < 4; ++nf)
        b[nf] = *(const bf16x8*)&Bs[(wn + nf * 16 + l16) * 64 + ko];
#pragma unroll
      for (int mf = 0; mf < 4; ++mf)
#pragma unroll
        for (int nf = 0; nf < 4; ++nf)
          acc[mf * 4 + nf] = __builtin_amdgcn_mfma_f32_16x16x32_bf16(
              a[mf], b[nf], acc[mf * 4 + nf], 0, 0, 0);
    }
    __syncthreads();
  }

#pragma unroll
  for (int mf = 0; mf < 4; ++mf) {
#pragma unroll
    for (int reg = 0; reg < 4; ++reg) {
      const int row = wm + mf * 16 + quad * 4 + reg;
      const int gr = m0 + row;
      if (gr < c) {
        const int ent = ents[row];
        const int t = ent >> 1;
        const float wgt = tokw[ent];
#pragma unroll
        for (int nf = 0; nf < 4; ++nf) {
          const int col = n0 + wn + nf * 16 + l16;
          float v = acc[mf * 4 + nf][reg];
          if (split == 0) v += b2[e * H_DIM + col];   // bias folded once
          atomicAdd(&out[(size_t)t * H_DIM + col], wgt * v);
        }
      }
    }
  }
}

// ================= Fallback path (no-prepass, used if ws too small) =================
__launch_bounds__(256)
__global__ void gemm1_fb_kernel(const float* __restrict__ x,
                                const float* __restrict__ W1,
                                const float* __restrict__ b1,
                                const int* __restrict__ cnt,
                                const int* __restrict__ base,
                                const int* __restrict__ list,
                                unsigned short* __restrict__ hmid) {
  const int e = blockIdx.z;
  const int c = cnt[e];
  const int m0 = blockIdx.y * 128;
  if (m0 >= c) return;
  const int n0 = blockIdx.x * 128;
  __shared__ int toks[128];
  __shared__ __align__(16) unsigned short As[128 * 40];
  __shared__ __align__(16) unsigned short Bs[128 * 40];
  const int tid = threadIdx.x;
  if (tid < 128) {
    int idx = m0 + tid; if (idx >= c) idx = c - 1;
    toks[tid] = list[e * CAP + idx] >> 1;
  }
  __syncthreads();
  const int lane = tid & 63, wave = tid >> 6;
  const int wm = (wave >> 1) * 64, wn = (wave & 1) * 64;
  const int l16 = lane & 15, quad = lane >> 4;
  f32x4 acc[16];
#pragma unroll
  for (int i = 0; i < 16; ++i) acc[i] = (f32x4){0.f, 0.f, 0.f, 0.f};
  const float* W1e = W1 + (size_t)e * H_DIM * I_DIM;
  for (int kt = 0; kt < H_DIM / 32; ++kt) {
    const int k0 = kt * 32;
#pragma unroll
    for (int i = 0; i < 2; ++i) {
      const int idx = tid + i * 256;
      const int row = idx >> 2, g = idx & 3;
      const float* src = x + (size_t)toks[row] * H_DIM + k0 + g * 8;
      const float4 v0 = *(const float4*)(src);
      const float4 v1 = *(const float4*)(src + 4);
      unsigned short tmp[8];
      tmp[0] = f2bf(v0.x); tmp[1] = f2bf(v0.y); tmp[2] = f2bf(v0.z); tmp[3] = f2bf(v0.w);
      tmp[4] = f2bf(v1.x); tmp[5] = f2bf(v1.y); tmp[6] = f2bf(v1.z); tmp[7] = f2bf(v1.w);
      *(f32x4*)&As[row * 40 + g * 8] = *(const f32x4*)tmp;
    }
#pragma unroll
    for (int i = 0; i < 2; ++i) {
      const int idx = tid + i * 256;
      const int n = idx & 127, g = idx >> 7;
      const float* src = W1e + (size_t)(k0 + g * 8) * I_DIM + n0 + n;
      unsigned short tmp[8];
#pragma unroll
      for (int kk = 0; kk < 8; ++kk) tmp[kk] = f2bf(src[(size_t)kk * I_DIM]);
      *(f32x4*)&Bs[n * 40 + g * 8] = *(const f32x4*)tmp;
    }
    __syncthreads();
    bf16x8 a[4], b[4];
#pragma unroll
    for (int mf = 0; mf < 4; ++mf)
      a[mf] = *(const bf16x8*)&As[(wm + mf * 16 + l16) * 40 + quad * 8];
#pragma unroll
    for (int nf = 0; nf < 4; ++nf)
      b[nf] = *(const bf16x8*)&Bs[(wn + nf * 16 + l16) * 40 + quad * 8];
#pragma unroll
    for (int mf = 0; mf < 4; ++mf)
#pragma unroll
      for (int nf = 0; nf < 4; ++nf)
        acc[mf * 4 + nf] = __builtin_amdgcn_mfma_f32_16x16x32_bf16(
            a[mf], b[nf], acc[mf * 4 + nf], 0, 0, 0);
    __syncthreads();
  }
  const int hb = base[e];
#pragma unroll
  for (int mf = 0; mf < 4; ++mf)
#pragma unroll
    for (int reg = 0; reg < 4; ++reg) {
      const int row = wm + mf * 16 + quad * 4 + reg;
      const int gr = m0 + row;
      if (gr < c) {
#pragma unroll
        for (int nf = 0; nf < 4; ++nf) {
          const int col = n0 + wn + nf * 16 + l16;
          const float v = acc[mf * 4 + nf][reg] + b1[e * I_DIM + col];
          const float u = v + 0.044715f * v * v * v;
          const float g = v / (1.f + __expf(-1.5957691216057308f * u));
          hmid[(size_t)(hb + gr) * I_DIM + col] = f2bf(g);
        }
      }
    }
}

__launch_bounds__(256)
__global__ void gemm2_fb_kernel(const unsigned short* __restrict__ hmid,
                                const float* __restrict__ W2,
                                const float* __restrict__ b2,
                                const int* __restrict__ cnt,
                                const int* __restrict__ base,
                                const int* __restrict__ list,
                                const float* __restrict__ tokw,
                                float* __restrict__ out) {
  const int e = blockIdx.z;
  const int c = cnt[e];
  const int m0 = blockIdx.y * 128;
  if (m0 >= c) return;
  const int n0 = blockIdx.x * 128;
  __shared__ int ents[128];
  __shared__ int arow[128];
  __shared__ __align__(16) unsigned short As[128 * 40];
  __shared__ __align__(16) unsigned short Bs[128 * 40];
  const int tid = threadIdx.x;
  const int hb = base[e];
  if (tid < 128) {
    int idx = m0 + tid; if (idx >= c) idx = c - 1;
    ents[tid] = list[e * CAP + idx];
    arow[tid] = hb + idx;
  }
  __syncthreads();
  const int lane = tid & 63, wave = tid >> 6;
  const int wm = (wave >> 1) * 64, wn = (wave & 1) * 64;
  const int l16 = lane & 15, quad = lane >> 4;
  f32x4 acc[16];
#pragma unroll
  for (int i = 0; i < 16; ++i) acc[i] = (f32x4){0.f, 0.f, 0.f, 0.f};
  const float* W2e = W2 + (size_t)e * I_DIM * H_DIM;
  for (int kt = 0; kt < I_DIM / 32; ++kt) {
    const int k0 = kt * 32;
#pragma unroll
    for (int i = 0; i < 2; ++i) {
      const int idx = tid + i * 256;
      const int row = idx >> 2, kg = idx & 3;
      const f32x4 v = *(const f32x4*)(hmid + (size_t)arow[row] * I_DIM + k0 + kg * 8);
      *(f32x4*)&As[row * 40 + kg * 8] = v;
    }
#pragma unroll
    for (int i = 0; i < 2; ++i) {
      const int idx = tid + i * 256;
      const int n = idx & 127, g = idx >> 7;
      const float* src = W2e + (size_t)(k0 + g * 8) * H_DIM + n0 + n;
      unsigned short tmp[8];
#pragma unroll
      for (int kk = 0; kk < 8; ++kk) tmp[kk] = f2bf(src[(size_t)kk * H_DIM]);
      *(f32x4*)&Bs[n * 40 + g * 8] = *(const f32x4*)tmp;
    }
    __syncthreads();
    bf16x8 a[4], b[4];
#pragma unroll
    for (int mf = 0; mf < 4; ++mf)
      a[mf] = *(const bf16x8*)&As[(wm + mf * 16 + l16) * 40 + quad * 8];
#pragma unroll
    for (int nf = 0; nf < 4; ++nf)
      b[nf] = *(const bf16x8*)&Bs[(wn + nf * 16 + l16) * 40 + quad * 8];
#pragma unroll
    for (int mf = 0; mf < 4; ++mf)
#pragma unroll
      for (int nf = 0; nf < 4; ++nf)
        acc[mf * 4 + nf] = __builtin_amdgcn_mfma_f32_16x16x32_bf16(
            a[mf], b[nf], acc[mf * 4 + nf], 0, 0, 0);
    __syncthreads();
  }
#pragma unroll
  for (int mf = 0; mf < 4; ++mf)
#pragma unroll
    for (int reg = 0; reg < 4; ++reg) {
      const int row = wm + mf * 16 + quad * 4 + reg;
      const int gr = m0 + row;
      if (gr < c) {
        const int ent = ents[row];
        const int t = ent >> 1;
        const float wgt = tokw[ent];
#pragma unroll
        for (int nf = 0; nf < 4; ++nf) {
          const int col = n0 + wn + nf * 16 + l16;
          const float v = acc[mf * 4 + nf][reg] + b2[e * H_DIM + col];
          atomicAdd(&out[(size_t)t * H_DIM + col], wgt * v);
        }
      }
    }
}

extern "C" void kernel_launch(void* const* d_in, const int* in_sizes, int n_in,
                              void* d_out, int out_size, void* d_ws, size_t ws_size,
                              hipStream_t stream) {
  (void)in_sizes; (void)n_in;
  const float* x  = (const float*)d_in[0];
  const float* gw = (const float*)d_in[1];
  const float* gb = (const float*)d_in[2];
  const float* W1 = (const float*)d_in[3];
  const float* b1 = (const float*)d_in[4];
  const float* W2 = (const float*)d_in[5];
  const float* b2 = (const float*)d_in[6];
  float* out = (float*)d_out;

  char* w = (char*)d_ws;
  int* cnt    = (int*)w;                                   // 32 B @ 0
  int* base   = (int*)(w + 32);                            // 32 B
  int* list   = (int*)(w + 256);                           // 256 KB -> 262400
  float* tokw = (float*)(w + 262400);                      // 32 KB  -> 295168
  unsigned short* hmid = (unsigned short*)(w + 295168);    // 64 MB  -> 67404032
  unsigned short* W1t  = (unsigned short*)(w + 67404032);  // 64 MB  -> 134512896
  unsigned short* W2t  = (unsigned short*)(w + 134512896); // 64 MB  -> 201621760
  unsigned short* xb   = (unsigned short*)(w + 201621760); // 8 MB   -> 210010368
  const size_t NEED = 210010368;
  const bool pre = (ws_size >= NEED);

  hipMemsetAsync(cnt, 0, 32, stream);
  hipMemsetAsync(out, 0, (size_t)out_size * sizeof(float), stream);

  router_kernel<<<T_NUM, 64, 0, stream>>>(x, gw, gb, cnt, list, tokw,
                                          pre ? xb : (unsigned short*)nullptr);
  scan_kernel<<<1, 64, 0, stream>>>(cnt, base);

  if (pre) {
    transpose_cvt_kernel<<<dim3(I_DIM / 128, H_DIM / 32, E_NUM), 256, 0, stream>>>(
        W1, W1t, H_DIM, I_DIM);
    transpose_cvt_kernel<<<dim3(H_DIM / 128, I_DIM / 32, E_NUM), 256, 0, stream>>>(
        W2, W2t, I_DIM, H_DIM);
    gemm1_pre_kernel<<<dim3(I_DIM / 128, CAP / 128, E_NUM), 256, 0, stream>>>(
        xb, W1t, b1, cnt, base, list, hmid);
    gemm2_pre_kernel<<<dim3(2 * (H_DIM / 128), CAP / 128, E_NUM), 256, 0, stream>>>(
        hmid, W2t, b2, cnt, base, list, tokw, out);
  } else {
    gemm1_fb_kernel<<<dim3(I_DIM / 128, CAP / 128, E_NUM), 256, 0, stream>>>(
        x, W1, b1, cnt, base, list, hmid);
    gemm2_fb_kernel<<<dim3(H_DIM / 128, CAP / 128, E_NUM), 256, 0, stream>>>(
        hmid, W2, b2, cnt, base, list, tokw, out);
  }
}